// Round 3
// baseline (413.587 us; speedup 1.0000x reference)
//
#include <hip/hip_runtime.h>

// InductionNetwork capsule routing, C=256, K=64, H=1024, 3 iterations.
// Monolithic zero-workspace design, one block per capsule group, all state in
// LDS. x_hat = enc @ W^T is never materialized:
//   c_hat[c,:] = W @ s,  s = sum_k d_k * enc[c,k,:]
//   b[c,k]    += enc[c,k,:] . u,  u = W^T @ c
// R2 post-mortem: NaN with zero-ws monolithic kernel => inputs are NOT bf16.
// Reference declares fp32; reading fp32 bits as bf16 makes NaNs from low
// mantissa halfwords (~2^-8 per element). This version votes on the storage
// dtype on-device (deterministic, graph-safe) and dispatches a templated
// fp32/bf16 routing routine; output dtype follows enc's dtype.

using f32x4  = __attribute__((ext_vector_type(4))) float;
using bf16x8 = __attribute__((ext_vector_type(8))) __bf16;
using bf16x2 = __attribute__((ext_vector_type(2))) __bf16;

struct Shared {
    float u[1024];     // u = W^T c (from previous iteration)
    float s[1024];     // weighted sum of encoder rows
    float c[1024];     // squashed capsule
    float chat[1024];  // W @ s
    float b[64];       // routing logits
    float d[64];       // softmax(b)
    float red[8];      // per-wave partial norms
};

template <typename T> struct IO;
template <> struct IO<float> {
    static __device__ inline void ld8(const float* p, float v[8]) {
        f32x4 a = *(const f32x4*)p;
        f32x4 b = *(const f32x4*)(p + 4);
        v[0]=a[0]; v[1]=a[1]; v[2]=a[2]; v[3]=a[3];
        v[4]=b[0]; v[5]=b[1]; v[6]=b[2]; v[7]=b[3];
    }
    static __device__ inline void ld2(const float* p, float& x, float& y) {
        float2 t = *(const float2*)p; x = t.x; y = t.y;
    }
    static __device__ inline void st2(float* p, float x, float y) {
        float2 t; t.x = x; t.y = y; *(float2*)p = t;
    }
};
template <> struct IO<__bf16> {
    static __device__ inline void ld8(const __bf16* p, float v[8]) {
        bf16x8 a = *(const bf16x8*)p;
        #pragma unroll
        for (int j = 0; j < 8; ++j) v[j] = (float)a[j];
    }
    static __device__ inline void ld2(const __bf16* p, float& x, float& y) {
        bf16x2 t = *(const bf16x2*)p; x = (float)t[0]; y = (float)t[1];
    }
    static __device__ inline void st2(__bf16* p, float x, float y) {
        bf16x2 t; t[0] = (__bf16)x; t[1] = (__bf16)y; *(bf16x2*)p = t;
    }
};

// TE: enc dtype, TW: W dtype, TO: out dtype. Body identical to R2's verified
// logic; only the global loads/stores are templated.
template <typename TE, typename TW, typename TO>
__device__ void route(const TE* __restrict__ erow, const TW* __restrict__ W,
                      TO* __restrict__ outrow, Shared& sh)
{
    const int t = threadIdx.x;
    const int lane = t & 63;
    const int w = t >> 6;           // 8 waves

    if (t < 64) sh.b[t] = 0.f;
    __syncthreads();

    for (int it = 0; it < 3; ++it) {
        // ---- b[k] += enc[k,:] . u  (u == 0 at it=0 -> skip) ----
        if (it > 0) {
            f32x4 uf[4];            // this lane's 16 u values, reused over k
            #pragma unroll
            for (int q = 0; q < 2; ++q) {
                uf[2*q]   = *(const f32x4*)&sh.u[q*512 + lane*8];
                uf[2*q+1] = *(const f32x4*)&sh.u[q*512 + lane*8 + 4];
            }
            for (int r = 0; r < 8; ++r) {
                const int k = w * 8 + r;
                const TE* ek = erow + (size_t)k * 1024;
                float sum = 0.f;
                #pragma unroll
                for (int q = 0; q < 2; ++q) {
                    float ev[8];
                    IO<TE>::ld8(ek + q*512 + lane*8, ev);
                    #pragma unroll
                    for (int j = 0; j < 8; ++j)
                        sum += ev[j] * uf[2*q + (j>>2)][j & 3];
                }
                #pragma unroll
                for (int off = 32; off; off >>= 1) sum += __shfl_xor(sum, off, 64);
                if (lane == 0) sh.b[k] += sum;
            }
            __syncthreads();
        }

        // ---- softmax over 64 logits (wave 0) ----
        if (t < 64) {
            float bv = sh.b[t];
            float m = bv;
            #pragma unroll
            for (int off = 32; off; off >>= 1) m = fmaxf(m, __shfl_xor(m, off, 64));
            float e = expf(bv - m);
            float sm = e;
            #pragma unroll
            for (int off = 32; off; off >>= 1) sm += __shfl_xor(sm, off, 64);
            sh.d[t] = e / sm;
        }
        __syncthreads();

        // ---- s[h] = sum_k d[k] * enc[k,h] ; thread owns h = 2t, 2t+1 ----
        {
            const int h0 = t * 2;
            float a0 = 0.f, a1 = 0.f;
            for (int k = 0; k < 64; ++k) {
                const float dk = sh.d[k];
                float x, y;
                IO<TE>::ld2(erow + (size_t)k * 1024 + h0, x, y);
                a0 += dk * x;
                a1 += dk * y;
            }
            sh.s[h0] = a0; sh.s[h0+1] = a1;
        }
        __syncthreads();

        // ---- chat[d] = W[d,:] . s ; wave w owns rows w*128..w*128+127 ----
        {
            f32x4 sf[4];
            #pragma unroll
            for (int q = 0; q < 2; ++q) {
                sf[2*q]   = *(const f32x4*)&sh.s[q*512 + lane*8];
                sf[2*q+1] = *(const f32x4*)&sh.s[q*512 + lane*8 + 4];
            }
            for (int r = 0; r < 128; ++r) {
                const int d = w * 128 + r;
                const TW* wr = W + (size_t)d * 1024;
                float sum = 0.f;
                #pragma unroll
                for (int q = 0; q < 2; ++q) {
                    float wv[8];
                    IO<TW>::ld8(wr + q*512 + lane*8, wv);
                    #pragma unroll
                    for (int j = 0; j < 8; ++j)
                        sum += wv[j] * sf[2*q + (j>>2)][j & 3];
                }
                #pragma unroll
                for (int off = 32; off; off >>= 1) sum += __shfl_xor(sum, off, 64);
                if (lane == 0) sh.chat[d] = sum;
            }
        }
        __syncthreads();

        // ---- squash ----
        {
            const int h0 = t * 2;
            float v0 = sh.chat[h0], v1 = sh.chat[h0+1];
            float ss = v0*v0 + v1*v1;
            #pragma unroll
            for (int off = 32; off; off >>= 1) ss += __shfl_xor(ss, off, 64);
            if (lane == 0) sh.red[w] = ss;
            __syncthreads();
            float norm = 0.f;
            #pragma unroll
            for (int i = 0; i < 8; ++i) norm += sh.red[i];
            const float scale = norm / ((1.f + norm) * sqrtf(norm) + 1e-30f);
            sh.c[h0]   = v0 * scale;
            sh.c[h0+1] = v1 * scale;
        }
        __syncthreads();

        if (it < 2) {
            // ---- u[h] = sum_d c[d] * W[d,h] ; thread owns h = 2t, 2t+1 ----
            const int h0 = t * 2;
            float u0 = 0.f, u1 = 0.f;
            for (int d = 0; d < 1024; ++d) {
                const float cd = sh.c[d];           // LDS broadcast
                float x, y;
                IO<TW>::ld2(W + (size_t)d * 1024 + h0, x, y);
                u0 += cd * x;
                u1 += cd * y;
            }
            sh.u[h0] = u0; sh.u[h0+1] = u1;
        } else {
            const int h0 = t * 2;
            IO<TO>::st2(outrow + h0, sh.c[h0], sh.c[h0+1]);
        }
        __syncthreads();
    }
}

// Deterministic storage-dtype vote: fp32 normal data lands in [2^-30, 2^30];
// bf16 pairs read as fp32 get their exponent field from a bf16's low bits ->
// magnitude ~2^125+/Inf/NaN. Wave-uniform, identical across blocks and calls.
__device__ inline bool looks_f32(const void* p) {
    const float* f = (const float*)p;
    float v = f[threadIdx.x & 63];
    float a = fabsf(v);
    bool ok = (a == 0.f) || (a > 9.3e-10f && a < 1.1e9f);
    unsigned long long m = __ballot(ok);
    return __popcll(m) >= 48;
}

__global__ __launch_bounds__(512) void capsule_route_kernel(
    const void* __restrict__ enc, const void* __restrict__ W,
    void* __restrict__ outp)
{
    __shared__ Shared sh;
    const bool e32 = looks_f32(enc);
    const bool w32 = looks_f32(W);
    const size_t c = blockIdx.x;

    if (e32 && w32) {
        route<float, float, float>((const float*)enc + c * 65536,
                                   (const float*)W,
                                   (float*)outp + c * 1024, sh);
    } else if (!e32 && !w32) {
        route<__bf16, __bf16, __bf16>((const __bf16*)enc + c * 65536,
                                      (const __bf16*)W,
                                      (__bf16*)outp + c * 1024, sh);
    } else if (e32) {
        route<float, __bf16, float>((const float*)enc + c * 65536,
                                    (const __bf16*)W,
                                    (float*)outp + c * 1024, sh);
    } else {
        route<__bf16, float, __bf16>((const __bf16*)enc + c * 65536,
                                     (const float*)W,
                                     (__bf16*)outp + c * 1024, sh);
    }
}

extern "C" void kernel_launch(void* const* d_in, const int* in_sizes, int n_in,
                              void* d_out, int out_size, void* d_ws, size_t ws_size,
                              hipStream_t stream)
{
    // d_in[0]: encoder_output [256,64,1024]; d_in[1]: W [1024,1024];
    // d_in[2]: iter_routing == 3 (hard-coded).
    (void)d_ws; (void)ws_size; (void)in_sizes; (void)n_in; (void)out_size;
    capsule_route_kernel<<<256, 512, 0, stream>>>(d_in[0], d_in[1], d_out);
}

// Round 6
// 309.342 us; speedup vs baseline: 1.3370x; 1.3370x over previous
//
#include <hip/hip_runtime.h>

// InductionNetwork capsule routing, C=256, K=64, H=1024, 3 iterations.
// fp32 in/out (R3). R4 post-mortem: MFMA layouts correct; bf16 operand
// rounding alone gave absmax 5.98e-3 (2x threshold) via softmax logit
// perturbation. Fix: split-bf16 GEMM operands (x = hi + lo, hi=bf16(x),
// lo=bf16(x-hi)); D = Ah.Bh + Ah.Bl + Al.Bh => fp32-accurate (~2^-17 rel)
// on the MFMA pipe. W pre-split direct+transposed once per launch.
// Fallback to R3's monolithic fp32 kernel if ws_size < 12.1 MB.
// R5: fixed compile error (reference binding to vector element) by making
// split_bf16 return a pair by value.

using f32x4  = __attribute__((ext_vector_type(4))) float;
using f32x2  = __attribute__((ext_vector_type(2))) float;
using bf16x8 = __attribute__((ext_vector_type(8))) __bf16;
using bf16x4 = __attribute__((ext_vector_type(4))) __bf16;
using bf16x2 = __attribute__((ext_vector_type(2))) __bf16;

struct BfPair { __bf16 hi, lo; };
__device__ inline BfPair split_bf16(float x) {
    BfPair p;
    p.hi = (__bf16)x;
    p.lo = (__bf16)(x - (float)p.hi);
    return p;
}

// ---------------- routing: b-update + softmax + weighted sum ----------------
// MODE 0: d uniform (iter 0).  MODE 1: b = E.u (store).  MODE 2: b += E.u.
template <int MODE>
__global__ __launch_bounds__(512) void routing_kernel(
    const float* __restrict__ enc, const float* __restrict__ u,
    float* __restrict__ bglob, __bf16* __restrict__ s_hi,
    __bf16* __restrict__ s_lo)
{
    __shared__ float spart[8][1024];   // per-wave partial s
    __shared__ float b_s[64];
    __shared__ float d_s[64];

    const int t = threadIdx.x, lane = t & 63, w = t >> 6;   // 8 waves
    const int c = blockIdx.x;
    const float* E = enc + (size_t)c * 65536;

    // Register-resident enc: wave w owns rows w*8..w*8+7; lane holds 16 floats
    // per row at h = {lane*8..+7, 512+lane*8..+7}.
    f32x4 er[8][4];
    #pragma unroll
    for (int r = 0; r < 8; ++r) {
        const float* ek = E + (size_t)(w * 8 + r) * 1024 + lane * 8;
        er[r][0] = *(const f32x4*)(ek);
        er[r][1] = *(const f32x4*)(ek + 4);
        er[r][2] = *(const f32x4*)(ek + 512);
        er[r][3] = *(const f32x4*)(ek + 516);
    }

    if (MODE > 0) {
        const float* up = u + (size_t)c * 1024 + lane * 8;
        f32x4 uf[4];
        uf[0] = *(const f32x4*)(up);
        uf[1] = *(const f32x4*)(up + 4);
        uf[2] = *(const f32x4*)(up + 512);
        uf[3] = *(const f32x4*)(up + 516);
        #pragma unroll
        for (int r = 0; r < 8; ++r) {
            float sum = 0.f;
            #pragma unroll
            for (int q = 0; q < 4; ++q)
                #pragma unroll
                for (int j = 0; j < 4; ++j)
                    sum += er[r][q][j] * uf[q][j];
            #pragma unroll
            for (int off = 32; off; off >>= 1) sum += __shfl_xor(sum, off, 64);
            if (lane == 0) {
                const int k = w * 8 + r;
                const float bv = (MODE == 2) ? (bglob[c * 64 + k] + sum) : sum;
                bglob[c * 64 + k] = bv;   // persist for next iteration
                b_s[k] = bv;
            }
        }
    }
    __syncthreads();

    if (MODE == 0) {
        if (t < 64) d_s[t] = 1.f / 64.f;
    } else if (t < 64) {
        float bv = b_s[t];
        float m = bv;
        #pragma unroll
        for (int off = 32; off; off >>= 1) m = fmaxf(m, __shfl_xor(m, off, 64));
        const float e = expf(bv - m);
        float sm = e;
        #pragma unroll
        for (int off = 32; off; off >>= 1) sm += __shfl_xor(sm, off, 64);
        d_s[t] = e / sm;
    }
    __syncthreads();

    // Per-wave partial s over this wave's 8 rows (from registers).
    #pragma unroll
    for (int q = 0; q < 4; ++q) {
        f32x4 p = {};
        #pragma unroll
        for (int r = 0; r < 8; ++r) {
            const float dk = d_s[w * 8 + r];
            #pragma unroll
            for (int j = 0; j < 4; ++j) p[j] += dk * er[r][q][j];
        }
        const int h = (q >> 1) * 512 + lane * 8 + (q & 1) * 4;
        *(f32x4*)&spart[w][h] = p;
    }
    __syncthreads();

    // Cross-wave reduce; emit split-bf16 s.
    const int h0 = t * 2;
    float a0 = 0.f, a1 = 0.f;
    #pragma unroll
    for (int wv = 0; wv < 8; ++wv) {
        f32x2 pv = *(const f32x2*)&spart[wv][h0];
        a0 += pv[0]; a1 += pv[1];
    }
    const BfPair p0 = split_bf16(a0);
    const BfPair p1 = split_bf16(a1);
    bf16x2 hv, lv;
    hv[0] = p0.hi; hv[1] = p1.hi;
    lv[0] = p0.lo; lv[1] = p1.lo;
    *(bf16x2*)(s_hi + (size_t)c * 1024 + h0) = hv;
    *(bf16x2*)(s_lo + (size_t)c * 1024 + h0) = lv;
}

// ---- split-bf16 NT GEMM: Cc[M,N] = (Ah+Al)[M,K] * (Bh+Bl)[N,K]^T, fp32 out.
// Fragment layout (verified R4: pure-precision failure => mapping correct):
// A[m=lane&15][k=(lane>>4)*8+j]; B[n=lane&15][k=...]; C/D col=lane&15,
// row=(lane>>4)*4+reg. D = Ah.Bh + Ah.Bl + Al.Bh (Al.Bl ~2^-18, dropped).
__global__ __launch_bounds__(64) void gemm_nt_split_kernel(
    const __bf16* __restrict__ Ah, const __bf16* __restrict__ Al,
    const __bf16* __restrict__ Bh, const __bf16* __restrict__ Bl,
    float* __restrict__ Cc, int M, int N, int K)
{
    const int mt = blockIdx.x, nt = blockIdx.y;
    const int lane = threadIdx.x;
    const size_t aoff = (size_t)(mt * 16 + (lane & 15)) * K + ((lane >> 4) * 8);
    const size_t boff = (size_t)(nt * 64 + (lane & 15)) * K + ((lane >> 4) * 8);

    f32x4 acc0 = {}, acc1 = {}, acc2 = {}, acc3 = {};
    for (int k0 = 0; k0 < K; k0 += 32) {
        bf16x8 ah = *(const bf16x8*)(Ah + aoff + k0);
        bf16x8 al = *(const bf16x8*)(Al + aoff + k0);
        #pragma unroll
        for (int j = 0; j < 4; ++j) {
            const size_t bo = boff + (size_t)j * 16 * K + k0;
            bf16x8 bh = *(const bf16x8*)(Bh + bo);
            bf16x8 bl = *(const bf16x8*)(Bl + bo);
            f32x4& acc = (j == 0) ? acc0 : (j == 1) ? acc1 : (j == 2) ? acc2 : acc3;
            acc = __builtin_amdgcn_mfma_f32_16x16x32_bf16(ah, bh, acc, 0, 0, 0);
            acc = __builtin_amdgcn_mfma_f32_16x16x32_bf16(ah, bl, acc, 0, 0, 0);
            acc = __builtin_amdgcn_mfma_f32_16x16x32_bf16(al, bh, acc, 0, 0, 0);
        }
    }

    const int rr = (lane >> 4) * 4;
    const int colb = lane & 15;
    f32x4 accs[4] = {acc0, acc1, acc2, acc3};
    #pragma unroll
    for (int j = 0; j < 4; j++) {
        const int col = nt * 64 + j * 16 + colb;
        #pragma unroll
        for (int r = 0; r < 4; r++)
            Cc[(size_t)(mt * 16 + rr + r) * N + col] = accs[j][r];
    }
}

// ---------------- squash: emits split-bf16 c + fp32 out ---------------------
__global__ __launch_bounds__(256) void squash_kernel(
    const float* __restrict__ chat, __bf16* __restrict__ c_hi,
    __bf16* __restrict__ c_lo, float* __restrict__ outp)
{
    __shared__ float wsum[4];
    const int c = blockIdx.x, t = threadIdx.x;
    const int lane = t & 63, w = t >> 6;
    const int h0 = t * 4;
    f32x4 v = *(const f32x4*)(chat + (size_t)c * 1024 + h0);
    float ss = v[0]*v[0] + v[1]*v[1] + v[2]*v[2] + v[3]*v[3];
    #pragma unroll
    for (int off = 32; off; off >>= 1) ss += __shfl_xor(ss, off, 64);
    if (lane == 0) wsum[w] = ss;
    __syncthreads();
    const float norm = wsum[0] + wsum[1] + wsum[2] + wsum[3];
    const float scale = norm / ((1.f + norm) * sqrtf(norm) + 1e-30f);
    f32x4 ov;
    bf16x4 hv, lv;
    #pragma unroll
    for (int j = 0; j < 4; ++j) {
        ov[j] = v[j] * scale;
        const BfPair p = split_bf16(ov[j]);
        hv[j] = p.hi;
        lv[j] = p.lo;
    }
    *(f32x4*)(outp + (size_t)c * 1024 + h0) = ov;
    *(bf16x4*)(c_hi + (size_t)c * 1024 + h0) = hv;
    *(bf16x4*)(c_lo + (size_t)c * 1024 + h0) = lv;
}

// ---------------- W -> split bf16, direct + transposed ----------------------
__global__ __launch_bounds__(256) void convert_w_kernel(
    const float* __restrict__ W, __bf16* __restrict__ Wb_hi,
    __bf16* __restrict__ Wb_lo, __bf16* __restrict__ Wt_hi,
    __bf16* __restrict__ Wt_lo)
{
    __shared__ float tile[64][65];
    const int bx = blockIdx.x, by = blockIdx.y;
    const int tx = threadIdx.x & 63, ty = threadIdx.x >> 6;
    for (int i = ty; i < 64; i += 4) {
        const size_t idx = (size_t)(by * 64 + i) * 1024 + bx * 64 + tx;
        const float v = W[idx];
        tile[i][tx] = v;
        const BfPair p = split_bf16(v);
        Wb_hi[idx] = p.hi; Wb_lo[idx] = p.lo;
    }
    __syncthreads();
    for (int i = ty; i < 64; i += 4) {
        const size_t idx = (size_t)(bx * 64 + i) * 1024 + by * 64 + tx;
        const BfPair p = split_bf16(tile[tx][i]);
        Wt_hi[idx] = p.hi; Wt_lo[idx] = p.lo;
    }
}

// ---------------- fallback: R3's proven monolithic fp32 kernel --------------
__global__ __launch_bounds__(512) void fallback_kernel(
    const float* __restrict__ enc, const float* __restrict__ W,
    float* __restrict__ outp)
{
    __shared__ float u_s[1024], s_s[1024], c_s[1024], chat_s[1024];
    __shared__ float b_s[64], d_s[64], red_s[8];
    const int t = threadIdx.x, lane = t & 63, w = t >> 6;
    const float* erow = enc + (size_t)blockIdx.x * 65536;

    if (t < 64) b_s[t] = 0.f;
    __syncthreads();

    for (int it = 0; it < 3; ++it) {
        if (it > 0) {
            f32x4 uf[4];
            #pragma unroll
            for (int q = 0; q < 2; ++q) {
                uf[2*q]   = *(const f32x4*)&u_s[q*512 + lane*8];
                uf[2*q+1] = *(const f32x4*)&u_s[q*512 + lane*8 + 4];
            }
            for (int r = 0; r < 8; ++r) {
                const int k = w * 8 + r;
                const float* ek = erow + (size_t)k * 1024;
                float sum = 0.f;
                #pragma unroll
                for (int q = 0; q < 2; ++q) {
                    f32x4 e0 = *(const f32x4*)(ek + q*512 + lane*8);
                    f32x4 e1 = *(const f32x4*)(ek + q*512 + lane*8 + 4);
                    #pragma unroll
                    for (int j = 0; j < 4; ++j) {
                        sum += e0[j] * uf[2*q][j];
                        sum += e1[j] * uf[2*q+1][j];
                    }
                }
                #pragma unroll
                for (int off = 32; off; off >>= 1) sum += __shfl_xor(sum, off, 64);
                if (lane == 0) b_s[k] += sum;
            }
            __syncthreads();
        }
        if (t < 64) {
            float bv = b_s[t], m = bv;
            #pragma unroll
            for (int off = 32; off; off >>= 1) m = fmaxf(m, __shfl_xor(m, off, 64));
            float e = expf(bv - m), sm = e;
            #pragma unroll
            for (int off = 32; off; off >>= 1) sm += __shfl_xor(sm, off, 64);
            d_s[t] = e / sm;
        }
        __syncthreads();
        {
            const int h0 = t * 2;
            float a0 = 0.f, a1 = 0.f;
            for (int k = 0; k < 64; ++k) {
                f32x2 ev = *(const f32x2*)(erow + (size_t)k * 1024 + h0);
                a0 += d_s[k] * ev[0]; a1 += d_s[k] * ev[1];
            }
            s_s[h0] = a0; s_s[h0+1] = a1;
        }
        __syncthreads();
        {
            f32x4 sf[4];
            #pragma unroll
            for (int q = 0; q < 2; ++q) {
                sf[2*q]   = *(const f32x4*)&s_s[q*512 + lane*8];
                sf[2*q+1] = *(const f32x4*)&s_s[q*512 + lane*8 + 4];
            }
            for (int r = 0; r < 128; ++r) {
                const int d = w * 128 + r;
                const float* wr = W + (size_t)d * 1024;
                float sum = 0.f;
                #pragma unroll
                for (int q = 0; q < 2; ++q) {
                    f32x4 w0 = *(const f32x4*)(wr + q*512 + lane*8);
                    f32x4 w1 = *(const f32x4*)(wr + q*512 + lane*8 + 4);
                    #pragma unroll
                    for (int j = 0; j < 4; ++j) {
                        sum += w0[j] * sf[2*q][j];
                        sum += w1[j] * sf[2*q+1][j];
                    }
                }
                #pragma unroll
                for (int off = 32; off; off >>= 1) sum += __shfl_xor(sum, off, 64);
                if (lane == 0) chat_s[d] = sum;
            }
        }
        __syncthreads();
        {
            const int h0 = t * 2;
            float v0 = chat_s[h0], v1 = chat_s[h0+1];
            float ss = v0*v0 + v1*v1;
            #pragma unroll
            for (int off = 32; off; off >>= 1) ss += __shfl_xor(ss, off, 64);
            if (lane == 0) red_s[w] = ss;
            __syncthreads();
            float norm = 0.f;
            #pragma unroll
            for (int i = 0; i < 8; ++i) norm += red_s[i];
            const float scale = norm / ((1.f + norm) * sqrtf(norm) + 1e-30f);
            c_s[h0] = v0 * scale; c_s[h0+1] = v1 * scale;
        }
        __syncthreads();
        if (it < 2) {
            const int h0 = t * 2;
            float u0 = 0.f, u1 = 0.f;
            for (int d = 0; d < 1024; ++d) {
                f32x2 wv = *(const f32x2*)(W + (size_t)d * 1024 + h0);
                u0 += c_s[d] * wv[0]; u1 += c_s[d] * wv[1];
            }
            u_s[h0] = u0; u_s[h0+1] = u1;
        } else {
            const int h0 = t * 2;
            f32x2 ov; ov[0] = c_s[h0]; ov[1] = c_s[h0+1];
            *(f32x2*)(outp + (size_t)blockIdx.x * 1024 + h0) = ov;
        }
        __syncthreads();
    }
}

extern "C" void kernel_launch(void* const* d_in, const int* in_sizes, int n_in,
                              void* d_out, int out_size, void* d_ws, size_t ws_size,
                              hipStream_t stream)
{
    const float* enc = (const float*)d_in[0];   // [256,64,1024] fp32
    const float* W   = (const float*)d_in[1];   // [1024,1024]   fp32
    float* outp = (float*)d_out;                // [256,1024]    fp32
    (void)in_sizes; (void)n_in; (void)out_size;

    // ws layout (12.06 MB)
    char* ws = (char*)d_ws;
    float*  b     = (float*) (ws + 0x000000);  //  64 KB [256,64]
    float*  u     = (float*) (ws + 0x010000);  //   1 MB [256,1024]
    float*  chat  = (float*) (ws + 0x110000);  //   1 MB [256,1024]
    __bf16* s_hi  = (__bf16*)(ws + 0x210000);  // 512 KB
    __bf16* s_lo  = (__bf16*)(ws + 0x290000);  // 512 KB
    __bf16* c_hi  = (__bf16*)(ws + 0x310000);  // 512 KB
    __bf16* c_lo  = (__bf16*)(ws + 0x390000);  // 512 KB
    __bf16* Wb_hi = (__bf16*)(ws + 0x410000);  //   2 MB [d,h]
    __bf16* Wb_lo = (__bf16*)(ws + 0x610000);  //   2 MB [d,h]
    __bf16* Wt_hi = (__bf16*)(ws + 0x810000);  //   2 MB [h,d]
    __bf16* Wt_lo = (__bf16*)(ws + 0xA10000);  //   2 MB [h,d]

    if (ws_size < 0xC10000) {
        fallback_kernel<<<256, 512, 0, stream>>>(enc, W, outp);
        return;
    }

    convert_w_kernel<<<dim3(16, 16), 256, 0, stream>>>(W, Wb_hi, Wb_lo,
                                                       Wt_hi, Wt_lo);

    // iter 0
    routing_kernel<0><<<256, 512, 0, stream>>>(enc, u, b, s_hi, s_lo);
    gemm_nt_split_kernel<<<dim3(16, 16), 64, 0, stream>>>(
        s_hi, s_lo, Wb_hi, Wb_lo, chat, 256, 1024, 1024);
    squash_kernel<<<256, 256, 0, stream>>>(chat, c_hi, c_lo, outp);
    gemm_nt_split_kernel<<<dim3(16, 16), 64, 0, stream>>>(
        c_hi, c_lo, Wt_hi, Wt_lo, u, 256, 1024, 1024);
    // iter 1
    routing_kernel<1><<<256, 512, 0, stream>>>(enc, u, b, s_hi, s_lo);
    gemm_nt_split_kernel<<<dim3(16, 16), 64, 0, stream>>>(
        s_hi, s_lo, Wb_hi, Wb_lo, chat, 256, 1024, 1024);
    squash_kernel<<<256, 256, 0, stream>>>(chat, c_hi, c_lo, outp);
    gemm_nt_split_kernel<<<dim3(16, 16), 64, 0, stream>>>(
        c_hi, c_lo, Wt_hi, Wt_lo, u, 256, 1024, 1024);
    // iter 2
    routing_kernel<2><<<256, 512, 0, stream>>>(enc, u, b, s_hi, s_lo);
    gemm_nt_split_kernel<<<dim3(16, 16), 64, 0, stream>>>(
        s_hi, s_lo, Wb_hi, Wb_lo, chat, 256, 1024, 1024);
    squash_kernel<<<256, 256, 0, stream>>>(chat, c_hi, c_lo, outp);
}